// Round 4
// baseline (493.164 us; speedup 1.0000x reference)
//
#include <hip/hip_runtime.h>

#define N_ROWS 32768
#define D_DIM  512
#define P_DIM  4096

#define OUT_LOGITS (32768LL * 512)
#define OUT_CVAE   (OUT_LOGITS + 32768LL * 4096)
#define OUT_PROT   (OUT_CVAE + 1)

typedef __attribute__((ext_vector_type(8))) short short8;
typedef __attribute__((ext_vector_type(4))) float f32x4;

__device__ __forceinline__ unsigned short f2bf(float f) {
  unsigned u = __float_as_uint(f);
  u = (u + 0x7FFFu + ((u >> 16) & 1u)) >> 16;
  return (unsigned short)u;
}

__device__ __forceinline__ void gload16(const void* g, void* l) {
  __builtin_amdgcn_global_load_lds((const __attribute__((address_space(1))) void*)g,
                                   (__attribute__((address_space(3))) void*)l,
                                   16, 0, 0);
}

// ---------------------------------------------------------------------------
// Prep: row L2-norm; writes bf16 copy in MFMA-fragment-major tiled layout
// (byte-identical to R1-R3 verified layout). One wave per row.
// ---------------------------------------------------------------------------
template <int NORM>
__global__ __launch_bounds__(256) void prep_kernel(const float* __restrict__ in,
                                                   float* __restrict__ outf,
                                                   unsigned short* __restrict__ outb,
                                                   float* __restrict__ n2) {
  int wave = threadIdx.x >> 6, lane = threadIdx.x & 63;
  int row  = blockIdx.x * 4 + wave;
  const float* p = in + (size_t)row * D_DIM + lane * 8;
  float4 v0 = *(const float4*)p;
  float4 v1 = *(const float4*)(p + 4);
  float ss = v0.x*v0.x + v0.y*v0.y + v0.z*v0.z + v0.w*v0.w
           + v1.x*v1.x + v1.y*v1.y + v1.z*v1.z + v1.w*v1.w;
#pragma unroll
  for (int m = 1; m < 64; m <<= 1) ss += __shfl_xor(ss, m);
  if (NORM) {
    float rinv = 1.0f / fmaxf(sqrtf(ss), 1e-12f);
    v0.x *= rinv; v0.y *= rinv; v0.z *= rinv; v0.w *= rinv;
    v1.x *= rinv; v1.y *= rinv; v1.z *= rinv; v1.w *= rinv;
    float4* qp = (float4*)(outf + (size_t)row * D_DIM + lane * 8);
    qp[0] = v0; qp[1] = v1;
  } else {
    if (lane == 0) n2[row] = ss;
  }
  uint4 b;
  b.x = (unsigned)f2bf(v0.x) | ((unsigned)f2bf(v0.y) << 16);
  b.y = (unsigned)f2bf(v0.z) | ((unsigned)f2bf(v0.w) << 16);
  b.z = (unsigned)f2bf(v1.x) | ((unsigned)f2bf(v1.y) << 16);
  b.w = (unsigned)f2bf(v1.z) | ((unsigned)f2bf(v1.w) << 16);
  int tile = row >> 8, mloc = (row >> 4) & 15, lrow = row & 15;
  size_t dst = ((size_t)(tile * 8 + (lane >> 3)) << 14)
             + (size_t)((((((lane >> 2) & 1) * 16 + mloc) * 64) + (lane & 3) * 16 + lrow) * 8);
  *(uint4*)(outb + dst) = b;
}

// ---------------------------------------------------------------------------
// PERSISTENT 256x256-tile GEMM: grid=256 (1 block/CU). Block b owns A-panel
// tm = (b&7)*16 + ((b>>3)&15) and walks 8 tiles tn = tnbase + s. Flat
// ktg = s*16+kt quad-buffer pipeline (BK=32, 4 x 32 KiB LDS) never drains
// across tile boundaries: epilogue C-stores overlap next tile's prefetch+MFMA.
// Counted vmcnt(8) steady state; vmcnt(16) at each tile's first kt to let
// epilogue stores drain in the background. w2 pre-staged to LDS.
// ---------------------------------------------------------------------------
__global__ __launch_bounds__(512) void gemm_fused(
    const unsigned short* __restrict__ A, const unsigned short* __restrict__ B,
    const float* __restrict__ w2, float* __restrict__ Cout,
    float* __restrict__ row_part, float* __restrict__ col_part) {
  __shared__ __align__(16) unsigned short S[4][16384];   // [buf][A 8192 | B 8192]
  __shared__ unsigned int rowmin_u[256];
  __shared__ unsigned int colmin_u[256];
  __shared__ __align__(16) float w2l[2048];

  const int tid = threadIdx.x;
  const int wave = tid >> 6, lane = tid & 63;
  const int q = lane >> 4, r16 = lane & 15;
  const int wr = wave >> 2, wc = wave & 3;

  const int b = blockIdx.x;
  const int xcd = b & 7, idx = b >> 3;
  const int tm = xcd * 16 + (idx & 15);        // fixed A-panel per block
  const int tnbase = (idx >> 4) * 8;           // tiles tn = tnbase..tnbase+7
  const int row0 = tm * 256;

  if (tid < 256) { rowmin_u[tid] = 0x7F800000u; colmin_u[tid] = 0x7F800000u; }

  const unsigned short* Ab = A + (size_t)tm * 131072;

  // stage w2 window (2048 floats) to LDS first — oldest VMEM ops, covered by
  // the pipeline's counted vmcnt waits long before first use.
  gload16(&w2[tnbase * 256 + tid * 4], (char*)w2l + tid * 16);

  f32x4 acc[8][4];
#pragma unroll
  for (int m = 0; m < 8; ++m)
#pragma unroll
    for (int n = 0; n < 4; ++n) acc[m][n] = (f32x4){0.f, 0.f, 0.f, 0.f};

  auto stg = [&](const unsigned short* ag, const unsigned short* bg, int bu, int p) {
    int c = (tid + p * 512) * 8;
    gload16(ag + c, &S[bu][0] + c);
    gload16(bg + c, &S[bu][8192] + c);
  };

  // prologue: 3 K-tiles in flight.
  {
    const unsigned short* Bb0 = B + (size_t)tnbase * 131072;
    stg(Ab,         Bb0,         0, 0); stg(Ab,         Bb0,         0, 1);
    stg(Ab + 8192,  Bb0 + 8192,  1, 0); stg(Ab + 8192,  Bb0 + 8192,  1, 1);
    stg(Ab + 16384, Bb0 + 16384, 2, 0); stg(Ab + 16384, Bb0 + 16384, 2, 1);
  }
  asm volatile("s_waitcnt vmcnt(8)" ::: "memory");
  __builtin_amdgcn_s_barrier();

  for (int s = 0; s < 8; ++s) {
    const int tn = tnbase + s;
    const int col0 = tn * 256;
    const unsigned short* BbS  = B + (size_t)tn * 131072;
    const unsigned short* BbS1 = BbS + 131072;          // only deref'd when s<7 || kt<13

#pragma unroll
    for (int kt = 0; kt < 16; ++kt) {
      const int cb = kt & 3;                            // ktg&3 == kt&3 (16%4==0)
      const unsigned short* al = &S[cb][0];
      const unsigned short* bl = &S[cb][8192];
      const int sb = (kt + 3) & 3;
      const unsigned short* ag = Ab + ((kt + 3) & 15) * 8192;
      const unsigned short* bg = (kt < 13 ? BbS : BbS1) + ((kt + 3) & 15) * 8192;
      const bool do_stg = (s < 7) || (kt < 13);
      short8 afr[4], bfr[4], afr2[4];

      // ---- phase 0: 8 ds_read_b128 + stage pass0; MFMA m0-3 x n0-3 ----
#pragma unroll
      for (int m = 0; m < 4; ++m)
        afr[m] = *(const short8*)(al + ((wr * 8 + m) * 64 + lane) * 8);
#pragma unroll
      for (int n = 0; n < 4; ++n)
        bfr[n] = *(const short8*)(bl + ((wc * 4 + n) * 64 + lane) * 8);
      if (do_stg) stg(ag, bg, sb, 0);
      __builtin_amdgcn_s_barrier();
      asm volatile("s_waitcnt lgkmcnt(0)" ::: "memory");
      __builtin_amdgcn_s_setprio(1);
#pragma unroll
      for (int m = 0; m < 4; ++m)
#pragma unroll
        for (int n = 0; n < 4; ++n)
          acc[m][n] = __builtin_amdgcn_mfma_f32_16x16x32_bf16(afr[m], bfr[n], acc[m][n], 0, 0, 0);
      __builtin_amdgcn_s_setprio(0);
      __builtin_amdgcn_s_barrier();

      // ---- phase 1: 4 ds_read_b128 + stage pass1 + counted vmcnt; MFMA m4-7
#pragma unroll
      for (int m = 0; m < 4; ++m)
        afr2[m] = *(const short8*)(al + ((wr * 8 + 4 + m) * 64 + lane) * 8);
      if (do_stg) stg(ag, bg, sb, 1);
      if (s == 7) {
        if (kt <= 12)      { asm volatile("s_waitcnt vmcnt(8)" ::: "memory"); }
        else if (kt == 13) { asm volatile("s_waitcnt vmcnt(4)" ::: "memory"); }
        else               { asm volatile("s_waitcnt vmcnt(0)" ::: "memory"); }
      } else if (kt == 0 && s > 0) {
        // epilogue stores of tile s-1 still outstanding; keep loads covered
        // (older stg(ktg+1), stg(ktg+2) forced complete) without draining.
        asm volatile("s_waitcnt vmcnt(16)" ::: "memory");
      } else {
        asm volatile("s_waitcnt vmcnt(8)" ::: "memory");
      }
      __builtin_amdgcn_s_barrier();
      asm volatile("s_waitcnt lgkmcnt(0)" ::: "memory");
      __builtin_amdgcn_s_setprio(1);
#pragma unroll
      for (int m = 0; m < 4; ++m)
#pragma unroll
        for (int n = 0; n < 4; ++n)
          acc[4 + m][n] = __builtin_amdgcn_mfma_f32_16x16x32_bf16(afr2[m], bfr[n], acc[4 + m][n], 0, 0, 0);
      __builtin_amdgcn_s_setprio(0);
      __builtin_amdgcn_s_barrier();
    }

    // ---- epilogue for tile (tm, tn): overlaps with already-issued prefetch
    float w2c[4];
#pragma unroll
    for (int n = 0; n < 4; ++n) w2c[n] = w2l[s * 256 + wc * 64 + n * 16 + r16];

    float rmin[8][4], cmin[4];
#pragma unroll
    for (int m = 0; m < 8; ++m)
#pragma unroll
      for (int j = 0; j < 4; ++j) rmin[m][j] = 1e30f;
#pragma unroll
    for (int n = 0; n < 4; ++n) cmin[n] = 1e30f;

#pragma unroll
    for (int m = 0; m < 8; ++m) {
      int grow = row0 + wr * 128 + m * 16 + q * 4;
#pragma unroll
      for (int n = 0; n < 4; ++n) {
        int gcol = col0 + wc * 64 + n * 16 + r16;
        f32x4 c = acc[m][n];
#pragma unroll
        for (int j = 0; j < 4; ++j) {
          float v = c[j];
          Cout[(size_t)(grow + j) * P_DIM + gcol] = v;
          float d2 = fmaxf(fmaf(-2.0f, v, 1.0f + w2c[n]), 0.0f);
          rmin[m][j] = fminf(rmin[m][j], d2);
          cmin[n] = fminf(cmin[n], d2);
        }
      }
    }
#pragma unroll
    for (int mask = 1; mask <= 8; mask <<= 1)
#pragma unroll
      for (int m = 0; m < 8; ++m)
#pragma unroll
        for (int j = 0; j < 4; ++j)
          rmin[m][j] = fminf(rmin[m][j], __shfl_xor(rmin[m][j], mask));
    if (r16 == 0) {
#pragma unroll
      for (int m = 0; m < 8; ++m)
#pragma unroll
        for (int j = 0; j < 4; ++j)
          atomicMin(&rowmin_u[wr * 128 + m * 16 + q * 4 + j], __float_as_uint(rmin[m][j]));
    }
#pragma unroll
    for (int mask = 16; mask <= 32; mask <<= 1)
#pragma unroll
      for (int n = 0; n < 4; ++n)
        cmin[n] = fminf(cmin[n], __shfl_xor(cmin[n], mask));
    if (q == 0) {
#pragma unroll
      for (int n = 0; n < 4; ++n)
        atomicMin(&colmin_u[wc * 64 + n * 16 + r16], __float_as_uint(cmin[n]));
    }
    __syncthreads();
    if (tid < 256) row_part[(size_t)tn * N_ROWS + row0 + tid] = __uint_as_float(rowmin_u[tid]);
    else           col_part[(size_t)tm * P_DIM + col0 + (tid - 256)] = __uint_as_float(colmin_u[tid - 256]);
    __syncthreads();
    if (tid < 256) { rowmin_u[tid] = 0x7F800000u; colmin_u[tid] = 0x7F800000u; }
#pragma unroll
    for (int m = 0; m < 8; ++m)
#pragma unroll
      for (int n = 0; n < 4; ++n) acc[m][n] = (f32x4){0.f, 0.f, 0.f, 0.f};
  }
}

// ---------------------------------------------------------------------------
__global__ __launch_bounds__(256) void minsqrt_sum(const float* __restrict__ part,
                                                   int nparts, int stride,
                                                   float* __restrict__ out) {
  int idx = blockIdx.x * 256 + threadIdx.x;
  float m = 1e30f;
  for (int p = 0; p < nparts; ++p) m = fminf(m, part[(size_t)p * stride + idx]);
  float s = sqrtf(m);
#pragma unroll
  for (int mask = 1; mask < 64; mask <<= 1) s += __shfl_xor(s, mask);
  __shared__ float wsum[4];
  int wave = threadIdx.x >> 6, lane = threadIdx.x & 63;
  if (lane == 0) wsum[wave] = s;
  __syncthreads();
  if (threadIdx.x == 0) out[blockIdx.x] = wsum[0] + wsum[1] + wsum[2] + wsum[3];
}

__global__ void finalize_kernel(const float* __restrict__ rowp, const float* __restrict__ colp,
                                const float* __restrict__ recon, const float* __restrict__ kl,
                                const float* __restrict__ mmd, float* __restrict__ out) {
  int lane = threadIdx.x;  // 64 threads
  float rs = rowp[lane] + rowp[lane + 64];
  float cs = (lane < 16) ? colp[lane] : 0.0f;
#pragma unroll
  for (int mask = 1; mask < 64; mask <<= 1) {
    rs += __shfl_xor(rs, mask);
    cs += __shfl_xor(cs, mask);
  }
  if (lane == 0) {
    out[OUT_CVAE] = recon[0] + 0.5f * kl[0] + mmd[0];
    out[OUT_PROT] = 0.5f * (rs / (float)N_ROWS) + 0.5f * (cs / (float)P_DIM);
  }
}

extern "C" void kernel_launch(void* const* d_in, const int* in_sizes, int n_in,
                              void* d_out, int out_size, void* d_ws, size_t ws_size,
                              hipStream_t stream) {
  const float* x     = (const float*)d_in[0];
  const float* W     = (const float*)d_in[1];
  const float* recon = (const float*)d_in[2];
  const float* kl    = (const float*)d_in[3];
  const float* mmd   = (const float*)d_in[4];
  float* out    = (float*)d_out;
  float* xn     = out;
  float* logits = out + OUT_LOGITS;

  char* ws = (char*)d_ws;
  unsigned short* Abf = (unsigned short*)ws;                 // 33,554,432 B
  unsigned short* Bbf = (unsigned short*)(ws + 33554432);    //  4,194,304 B
  float* w2       = (float*)(ws + 37748736);                 //     16,384 B
  float* row_part = (float*)(ws + 37765120);                 //  2,097,152 B (16 x 32768)
  float* col_part = (float*)(ws + 39862272);                 //  2,097,152 B (128 x 4096)
  float* rowsums  = (float*)(ws + 41959424);                 //        512 B
  float* colsums  = (float*)(ws + 41959936);                 //         64 B

  prep_kernel<1><<<N_ROWS / 4, 256, 0, stream>>>(x, xn, Abf, nullptr);
  prep_kernel<0><<<P_DIM / 4, 256, 0, stream>>>(W, nullptr, Bbf, w2);
  gemm_fused<<<256, 512, 0, stream>>>(Abf, Bbf, w2, logits, row_part, col_part);
  minsqrt_sum<<<N_ROWS / 256, 256, 0, stream>>>(row_part, 16, N_ROWS, rowsums);
  minsqrt_sum<<<P_DIM / 256, 256, 0, stream>>>(col_part, 128, P_DIM, colsums);
  finalize_kernel<<<1, 64, 0, stream>>>(rowsums, colsums, recon, kl, mmd, out);
}

// Round 5
// 428.443 us; speedup vs baseline: 1.1511x; 1.1511x over previous
//
#include <hip/hip_runtime.h>

#define N_ROWS 32768
#define D_DIM  512
#define P_DIM  4096

#define OUT_LOGITS (32768LL * 512)
#define OUT_CVAE   (OUT_LOGITS + 32768LL * 4096)
#define OUT_PROT   (OUT_CVAE + 1)

typedef __attribute__((ext_vector_type(8))) short short8;
typedef __attribute__((ext_vector_type(4))) float f32x4;

__device__ __forceinline__ unsigned short f2bf(float f) {
  unsigned u = __float_as_uint(f);
  u = (u + 0x7FFFu + ((u >> 16) & 1u)) >> 16;
  return (unsigned short)u;
}

__device__ __forceinline__ void gload16(const void* g, void* l) {
  __builtin_amdgcn_global_load_lds((const __attribute__((address_space(1))) void*)g,
                                   (__attribute__((address_space(3))) void*)l,
                                   16, 0, 0);
}

// ---------------------------------------------------------------------------
// Prep: row L2-norm; bf16 copy in 128-row-tile fragment-major layout:
// elem[(tile*16 + kt)*4096 + (fr*64 + kq*16 + r)*8 + e]
// with row = tile*128 + fr*16 + r, k = kt*32 + kq*8 + e.
// One wave per row; lane j holds k = j*8..j*8+7 (kt=j>>2, kq=j&3).
// ---------------------------------------------------------------------------
template <int NORM>
__global__ __launch_bounds__(256) void prep_kernel(const float* __restrict__ in,
                                                   float* __restrict__ outf,
                                                   unsigned short* __restrict__ outb,
                                                   float* __restrict__ n2) {
  int wave = threadIdx.x >> 6, lane = threadIdx.x & 63;
  int row  = blockIdx.x * 4 + wave;
  const float* p = in + (size_t)row * D_DIM + lane * 8;
  float4 v0 = *(const float4*)p;
  float4 v1 = *(const float4*)(p + 4);
  float ss = v0.x*v0.x + v0.y*v0.y + v0.z*v0.z + v0.w*v0.w
           + v1.x*v1.x + v1.y*v1.y + v1.z*v1.z + v1.w*v1.w;
#pragma unroll
  for (int m = 1; m < 64; m <<= 1) ss += __shfl_xor(ss, m);
  if (NORM) {
    float rinv = 1.0f / fmaxf(sqrtf(ss), 1e-12f);
    v0.x *= rinv; v0.y *= rinv; v0.z *= rinv; v0.w *= rinv;
    v1.x *= rinv; v1.y *= rinv; v1.z *= rinv; v1.w *= rinv;
    float4* qp = (float4*)(outf + (size_t)row * D_DIM + lane * 8);
    qp[0] = v0; qp[1] = v1;
  } else {
    if (lane == 0) n2[row] = ss;
  }
  uint4 b;
  b.x = (unsigned)f2bf(v0.x) | ((unsigned)f2bf(v0.y) << 16);
  b.y = (unsigned)f2bf(v0.z) | ((unsigned)f2bf(v0.w) << 16);
  b.z = (unsigned)f2bf(v1.x) | ((unsigned)f2bf(v1.y) << 16);
  b.w = (unsigned)f2bf(v1.z) | ((unsigned)f2bf(v1.w) << 16);
  int tile = row >> 7, fr = (row >> 4) & 7, r = row & 15;
  size_t dst = (size_t)(tile * 16 + (lane >> 2)) * 4096
             + (size_t)((fr * 64 + (lane & 3) * 16 + r) * 8);
  *(uint4*)(outb + dst) = b;
}

// ---------------------------------------------------------------------------
// 128x128-tile GEMM (m97 structure): 4 waves, BK=32, 2x16KB LDS dbuf,
// global_load_lds staging, one __syncthreads per K-step, ~3 blocks/CU TLP.
// MFMA operands: A = W-frag, B = xn-frag  ->  lane's f32x4 acc spans 4
// consecutive logits COLUMNS -> coalesced dwordx4 C-stores, no transpose.
// XCD mapping: XCD (b&7) owns W-tiles 4x..4x+3 (L2-resident); x-tiles sweep.
// Fused epilogue: d2 = 1 + |W_j|^2 - 2*logit; row-min (over w) / col-min
// (over x) partials.
// ---------------------------------------------------------------------------
__global__ __launch_bounds__(256, 3) void gemm_fused(
    const unsigned short* __restrict__ Wb, const unsigned short* __restrict__ Xb,
    const float* __restrict__ w2, float* __restrict__ Cout,
    float* __restrict__ row_part, float* __restrict__ col_part) {
  __shared__ __align__(16) unsigned short SA[2][4096];   // W tile 128x32
  __shared__ __align__(16) unsigned short SB[2][4096];   // x tile 128x32
  __shared__ unsigned int rowmin_u[128];                 // per x-row
  __shared__ unsigned int colmin_u[128];                 // per w-col

  const int tid = threadIdx.x;
  const int wave = tid >> 6, lane = tid & 63;
  const int q = lane >> 4, r16 = lane & 15;
  const int ww = wave >> 1, wx = wave & 1;

  const int b = blockIdx.x;
  const int tw = (b & 7) * 4 + ((b >> 3) & 3);   // 0..31 (XCD-pinned W column)
  const int tx = b >> 5;                         // 0..255
  const int w0 = tw * 128, x0 = tx * 128;

  if (tid < 128) { rowmin_u[tid] = 0x7F800000u; colmin_u[tid] = 0x7F800000u; }

  const unsigned short* Wg = Wb + (size_t)(tw * 16) * 4096;
  const unsigned short* Xg = Xb + (size_t)(tx * 16) * 4096;

  f32x4 acc[4][4];
#pragma unroll
  for (int m = 0; m < 4; ++m)
#pragma unroll
    for (int n = 0; n < 4; ++n) acc[m][n] = (f32x4){0.f, 0.f, 0.f, 0.f};

  auto stg = [&](int kt, int bu) {
#pragma unroll
    for (int i = 0; i < 2; ++i) {
      int c = (tid + 256 * i) * 8;
      gload16(Wg + (size_t)kt * 4096 + c, &SA[bu][0] + c);
      gload16(Xg + (size_t)kt * 4096 + c, &SB[bu][0] + c);
    }
  };

  stg(0, 0);
  __syncthreads();

  int cur = 0;
#pragma unroll
  for (int kt = 0; kt < 16; ++kt) {
    if (kt < 15) stg(kt + 1, cur ^ 1);
    short8 af[4], bf[4];
#pragma unroll
    for (int m = 0; m < 4; ++m)
      af[m] = *(const short8*)(&SA[cur][0] + ((ww * 4 + m) * 64 + lane) * 8);
#pragma unroll
    for (int n = 0; n < 4; ++n)
      bf[n] = *(const short8*)(&SB[cur][0] + ((wx * 4 + n) * 64 + lane) * 8);
    __builtin_amdgcn_s_setprio(1);
#pragma unroll
    for (int m = 0; m < 4; ++m)
#pragma unroll
      for (int n = 0; n < 4; ++n)
        acc[m][n] = __builtin_amdgcn_mfma_f32_16x16x32_bf16(af[m], bf[n], acc[m][n], 0, 0, 0);
    __builtin_amdgcn_s_setprio(0);
    __syncthreads();                 // drains vmcnt (staged kt+1) + WAR-safe
    cur ^= 1;
  }

  // ---- epilogue: coalesced float4 stores + fused d2 mins ----
  float rmin[4];                      // per n (x-rows)
  float cmin[4][4];                   // per m,j (w-cols)
#pragma unroll
  for (int n = 0; n < 4; ++n) rmin[n] = 1e30f;
#pragma unroll
  for (int m = 0; m < 4; ++m)
#pragma unroll
    for (int j = 0; j < 4; ++j) cmin[m][j] = 1e30f;

  const float* w2p = w2 + w0 + ww * 64;
#pragma unroll
  for (int m = 0; m < 4; ++m) {
    float4 w2v = *(const float4*)(w2p + m * 16 + q * 4);
    const size_t wcol = (size_t)(w0 + ww * 64 + m * 16 + q * 4);
#pragma unroll
    for (int n = 0; n < 4; ++n) {
      f32x4 c = acc[m][n];
      int xr = x0 + wx * 64 + n * 16 + r16;
      float4 st; st.x = c[0]; st.y = c[1]; st.z = c[2]; st.w = c[3];
      *(float4*)&Cout[(size_t)xr * P_DIM + wcol] = st;
      float d0 = fmaxf(fmaf(-2.f, c[0], 1.f + w2v.x), 0.f);
      float d1 = fmaxf(fmaf(-2.f, c[1], 1.f + w2v.y), 0.f);
      float d2 = fmaxf(fmaf(-2.f, c[2], 1.f + w2v.z), 0.f);
      float d3 = fmaxf(fmaf(-2.f, c[3], 1.f + w2v.w), 0.f);
      rmin[n] = fminf(rmin[n], fminf(fminf(d0, d1), fminf(d2, d3)));
      cmin[m][0] = fminf(cmin[m][0], d0);
      cmin[m][1] = fminf(cmin[m][1], d1);
      cmin[m][2] = fminf(cmin[m][2], d2);
      cmin[m][3] = fminf(cmin[m][3], d3);
    }
  }
  // row-min: reduce across q (same x-row for equal r16)
#pragma unroll
  for (int mask = 16; mask <= 32; mask <<= 1)
#pragma unroll
    for (int n = 0; n < 4; ++n)
      rmin[n] = fminf(rmin[n], __shfl_xor(rmin[n], mask));
  if (q == 0) {
#pragma unroll
    for (int n = 0; n < 4; ++n)
      atomicMin(&rowmin_u[wx * 64 + n * 16 + r16], __float_as_uint(rmin[n]));
  }
  // col-min: reduce across r16 (same w-col for equal q)
#pragma unroll
  for (int mask = 1; mask <= 8; mask <<= 1)
#pragma unroll
    for (int m = 0; m < 4; ++m)
#pragma unroll
      for (int j = 0; j < 4; ++j)
        cmin[m][j] = fminf(cmin[m][j], __shfl_xor(cmin[m][j], mask));
  if (r16 == 0) {
#pragma unroll
    for (int m = 0; m < 4; ++m)
#pragma unroll
      for (int j = 0; j < 4; ++j)
        atomicMin(&colmin_u[ww * 64 + m * 16 + q * 4 + j], __float_as_uint(cmin[m][j]));
  }
  __syncthreads();
  if (tid < 128) row_part[(size_t)tw * N_ROWS + x0 + tid] = __uint_as_float(rowmin_u[tid]);
  else           col_part[(size_t)tx * P_DIM + w0 + (tid - 128)] = __uint_as_float(colmin_u[tid - 128]);
}

// ---------------------------------------------------------------------------
__global__ __launch_bounds__(256) void minsqrt_sum(const float* __restrict__ part,
                                                   int nparts, int stride,
                                                   float* __restrict__ out) {
  int idx = blockIdx.x * 256 + threadIdx.x;
  float m = 1e30f;
  for (int p = 0; p < nparts; ++p) m = fminf(m, part[(size_t)p * stride + idx]);
  float s = sqrtf(m);
#pragma unroll
  for (int mask = 1; mask < 64; mask <<= 1) s += __shfl_xor(s, mask);
  __shared__ float wsum[4];
  int wave = threadIdx.x >> 6, lane = threadIdx.x & 63;
  if (lane == 0) wsum[wave] = s;
  __syncthreads();
  if (threadIdx.x == 0) out[blockIdx.x] = wsum[0] + wsum[1] + wsum[2] + wsum[3];
}

__global__ void finalize_kernel(const float* __restrict__ rowp, const float* __restrict__ colp,
                                const float* __restrict__ recon, const float* __restrict__ kl,
                                const float* __restrict__ mmd, float* __restrict__ out) {
  int lane = threadIdx.x;  // 64 threads
  float rs = rowp[lane] + rowp[lane + 64];
  float cs = (lane < 16) ? colp[lane] : 0.0f;
#pragma unroll
  for (int mask = 1; mask < 64; mask <<= 1) {
    rs += __shfl_xor(rs, mask);
    cs += __shfl_xor(cs, mask);
  }
  if (lane == 0) {
    out[OUT_CVAE] = recon[0] + 0.5f * kl[0] + mmd[0];
    out[OUT_PROT] = 0.5f * (rs / (float)N_ROWS) + 0.5f * (cs / (float)P_DIM);
  }
}

extern "C" void kernel_launch(void* const* d_in, const int* in_sizes, int n_in,
                              void* d_out, int out_size, void* d_ws, size_t ws_size,
                              hipStream_t stream) {
  const float* x     = (const float*)d_in[0];
  const float* W     = (const float*)d_in[1];
  const float* recon = (const float*)d_in[2];
  const float* kl    = (const float*)d_in[3];
  const float* mmd   = (const float*)d_in[4];
  float* out    = (float*)d_out;
  float* xn     = out;
  float* logits = out + OUT_LOGITS;

  char* ws = (char*)d_ws;
  unsigned short* Xbf = (unsigned short*)ws;                 // 33,554,432 B
  unsigned short* Wbf = (unsigned short*)(ws + 33554432);    //  4,194,304 B
  float* w2       = (float*)(ws + 37748736);                 //     16,384 B
  float* row_part = (float*)(ws + 37765120);                 //  4,194,304 B (32 x 32768)
  float* col_part = (float*)(ws + 41959424);                 //  4,194,304 B (256 x 4096)
  float* rowsums  = (float*)(ws + 46153728);                 //        512 B
  float* colsums  = (float*)(ws + 46154240);                 //         64 B

  prep_kernel<1><<<N_ROWS / 4, 256, 0, stream>>>(x, xn, Xbf, nullptr);
  prep_kernel<0><<<P_DIM / 4, 256, 0, stream>>>(W, nullptr, Wbf, w2);
  gemm_fused<<<(N_ROWS / 128) * (P_DIM / 128), 256, 0, stream>>>(
      Wbf, Xbf, w2, logits, row_part, col_part);
  minsqrt_sum<<<N_ROWS / 256, 256, 0, stream>>>(row_part, 32, N_ROWS, rowsums);
  minsqrt_sum<<<P_DIM / 256, 256, 0, stream>>>(col_part, 256, P_DIM, colsums);
  finalize_kernel<<<1, 64, 0, stream>>>(rowsums, colsums, recon, kl, mmd, out);
}

// Round 7
// 252.042 us; speedup vs baseline: 1.9567x; 1.6999x over previous
//
#include <hip/hip_runtime.h>

#define N_ROWS 32768
#define D_DIM  512
#define P_DIM  4096

#define OUT_LOGITS (32768LL * 512)
#define OUT_CVAE   (OUT_LOGITS + 32768LL * 4096)
#define OUT_PROT   (OUT_CVAE + 1)

typedef __attribute__((ext_vector_type(8))) short short8;
typedef __attribute__((ext_vector_type(4))) float f32x4;

__device__ __forceinline__ unsigned short f2bf(float f) {
  unsigned u = __float_as_uint(f);
  u = (u + 0x7FFFu + ((u >> 16) & 1u)) >> 16;
  return (unsigned short)u;
}

__device__ __forceinline__ void gload16(const void* g, void* l) {
  __builtin_amdgcn_global_load_lds((const __attribute__((address_space(1))) void*)g,
                                   (__attribute__((address_space(3))) void*)l,
                                   16, 0, 0);
}

// ---------------------------------------------------------------------------
// Prep: row L2-norm; bf16 copy in 128-row-tile fragment-major layout
// (identical to R5). xn written with non-temporal stores (never re-read;
// keeps L2/L3 clean for the staged bf16 operands).
// ---------------------------------------------------------------------------
template <int NORM>
__global__ __launch_bounds__(256) void prep_kernel(const float* __restrict__ in,
                                                   float* __restrict__ outf,
                                                   unsigned short* __restrict__ outb,
                                                   float* __restrict__ n2) {
  int wave = threadIdx.x >> 6, lane = threadIdx.x & 63;
  int row  = blockIdx.x * 4 + wave;
  const float* p = in + (size_t)row * D_DIM + lane * 8;
  float4 v0 = *(const float4*)p;
  float4 v1 = *(const float4*)(p + 4);
  float ss = v0.x*v0.x + v0.y*v0.y + v0.z*v0.z + v0.w*v0.w
           + v1.x*v1.x + v1.y*v1.y + v1.z*v1.z + v1.w*v1.w;
#pragma unroll
  for (int m = 1; m < 64; m <<= 1) ss += __shfl_xor(ss, m);
  if (NORM) {
    float rinv = 1.0f / fmaxf(sqrtf(ss), 1e-12f);
    v0.x *= rinv; v0.y *= rinv; v0.z *= rinv; v0.w *= rinv;
    v1.x *= rinv; v1.y *= rinv; v1.z *= rinv; v1.w *= rinv;
    f32x4* qp = (f32x4*)(outf + (size_t)row * D_DIM + lane * 8);
    f32x4 a0 = {v0.x, v0.y, v0.z, v0.w};
    f32x4 a1 = {v1.x, v1.y, v1.z, v1.w};
    __builtin_nontemporal_store(a0, qp);
    __builtin_nontemporal_store(a1, qp + 1);
  } else {
    if (lane == 0) n2[row] = ss;
  }
  uint4 b;
  b.x = (unsigned)f2bf(v0.x) | ((unsigned)f2bf(v0.y) << 16);
  b.y = (unsigned)f2bf(v0.z) | ((unsigned)f2bf(v0.w) << 16);
  b.z = (unsigned)f2bf(v1.x) | ((unsigned)f2bf(v1.y) << 16);
  b.w = (unsigned)f2bf(v1.z) | ((unsigned)f2bf(v1.w) << 16);
  int tile = row >> 7, fr = (row >> 4) & 7, r = row & 15;
  size_t dst = (size_t)(tile * 16 + (lane >> 2)) * 4096
             + (size_t)((fr * 64 + (lane & 3) * 16 + r) * 8);
  *(uint4*)(outb + dst) = b;
}

__global__ __launch_bounds__(256) void init_mins(unsigned int* __restrict__ p, int n) {
  int i = blockIdx.x * 256 + threadIdx.x;
  if (i < n) p[i] = 0x7F800000u;   // +inf
}

// ---------------------------------------------------------------------------
// 128x128-tile GEMM: 4 waves, BK=32, TRIPLE-buffered LDS (3 x 16 KB), one
// s_barrier per K-step, counted vmcnt(4) (vmcnt(0) only at the tail).
// WAR-safe by 3-buffering: stg(kt+2) writes the buffer last read at kt-1,
// and every wave is past its kt-1 reads once it passes the kt-top barrier.
// A = W-frag, B = xn-frag -> lane's f32x4 acc spans 4 consecutive logits
// cols -> NON-TEMPORAL dwordx4 stores (write stream bypasses cache).
// Fused epilogue: d2 = 1 + |W_j|^2 - 2*logit; block-reduced mins go to
// GLOBAL atomicMin (bitwise-deterministic).
// ---------------------------------------------------------------------------
__global__ __launch_bounds__(256, 3) void gemm_fused(
    const unsigned short* __restrict__ Wb, const unsigned short* __restrict__ Xb,
    const float* __restrict__ w2, float* __restrict__ Cout,
    unsigned int* __restrict__ rowmin_g, unsigned int* __restrict__ colmin_g) {
  __shared__ __align__(16) unsigned short SA[3][4096];   // W tile 128x32
  __shared__ __align__(16) unsigned short SB[3][4096];   // x tile 128x32
  __shared__ unsigned int rowmin_u[128];                 // per x-row
  __shared__ unsigned int colmin_u[128];                 // per w-col

  const int tid = threadIdx.x;
  const int wave = tid >> 6, lane = tid & 63;
  const int q = lane >> 4, r16 = lane & 15;
  const int ww = wave >> 1, wx = wave & 1;

  const int b = blockIdx.x;
  const int tw = (b & 7) * 4 + ((b >> 3) & 3);   // 0..31 (XCD-pinned W column)
  const int tx = b >> 5;                         // 0..255
  const int w0 = tw * 128, x0 = tx * 128;

  if (tid < 128) { rowmin_u[tid] = 0x7F800000u; colmin_u[tid] = 0x7F800000u; }

  const unsigned short* Wg = Wb + (size_t)(tw * 16) * 4096;
  const unsigned short* Xg = Xb + (size_t)(tx * 16) * 4096;

  f32x4 acc[4][4];
#pragma unroll
  for (int m = 0; m < 4; ++m)
#pragma unroll
    for (int n = 0; n < 4; ++n) acc[m][n] = (f32x4){0.f, 0.f, 0.f, 0.f};

  auto stg = [&](int kt, int bu) {   // 4 gload_lds per thread
#pragma unroll
    for (int i = 0; i < 2; ++i) {
      int c = (tid + 256 * i) * 8;
      gload16(Wg + (size_t)kt * 4096 + c, &SA[bu][0] + c);
      gload16(Xg + (size_t)kt * 4096 + c, &SB[bu][0] + c);
    }
  };

  stg(0, 0);
  stg(1, 1);

#pragma unroll
  for (int kt = 0; kt < 16; ++kt) {
    const int cur = kt % 3;
    if (kt < 15) { asm volatile("s_waitcnt vmcnt(4)" ::: "memory"); }
    else         { asm volatile("s_waitcnt vmcnt(0)" ::: "memory"); }
    __builtin_amdgcn_s_barrier();

    short8 af[4], bf[4];
#pragma unroll
    for (int m = 0; m < 4; ++m)
      af[m] = *(const short8*)(&SA[cur][0] + ((ww * 4 + m) * 64 + lane) * 8);
#pragma unroll
    for (int n = 0; n < 4; ++n)
      bf[n] = *(const short8*)(&SB[cur][0] + ((wx * 4 + n) * 64 + lane) * 8);
    if (kt < 14) stg(kt + 2, (kt + 2) % 3);

    __builtin_amdgcn_s_setprio(1);
#pragma unroll
    for (int m = 0; m < 4; ++m)
#pragma unroll
      for (int n = 0; n < 4; ++n)
        acc[m][n] = __builtin_amdgcn_mfma_f32_16x16x32_bf16(af[m], bf[n], acc[m][n], 0, 0, 0);
    __builtin_amdgcn_s_setprio(0);
  }

  // ---- epilogue: non-temporal float4 stores + fused d2 mins ----
  float rmin[4];                      // per n (x-rows)
  float cmin[4][4];                   // per m,j (w-cols)
#pragma unroll
  for (int n = 0; n < 4; ++n) rmin[n] = 1e30f;
#pragma unroll
  for (int m = 0; m < 4; ++m)
#pragma unroll
    for (int j = 0; j < 4; ++j) cmin[m][j] = 1e30f;

  const float* w2p = w2 + w0 + ww * 64;
#pragma unroll
  for (int m = 0; m < 4; ++m) {
    float4 w2v = *(const float4*)(w2p + m * 16 + q * 4);
    const size_t wcol = (size_t)(w0 + ww * 64 + m * 16 + q * 4);
#pragma unroll
    for (int n = 0; n < 4; ++n) {
      f32x4 c = acc[m][n];
      int xr = x0 + wx * 64 + n * 16 + r16;
      __builtin_nontemporal_store(c, (f32x4*)&Cout[(size_t)xr * P_DIM + wcol]);
      float d0 = fmaxf(fmaf(-2.f, c[0], 1.f + w2v.x), 0.f);
      float d1 = fmaxf(fmaf(-2.f, c[1], 1.f + w2v.y), 0.f);
      float d2 = fmaxf(fmaf(-2.f, c[2], 1.f + w2v.z), 0.f);
      float d3 = fmaxf(fmaf(-2.f, c[3], 1.f + w2v.w), 0.f);
      rmin[n] = fminf(rmin[n], fminf(fminf(d0, d1), fminf(d2, d3)));
      cmin[m][0] = fminf(cmin[m][0], d0);
      cmin[m][1] = fminf(cmin[m][1], d1);
      cmin[m][2] = fminf(cmin[m][2], d2);
      cmin[m][3] = fminf(cmin[m][3], d3);
    }
  }
  // row-min: reduce across q (same x-row for equal r16)
#pragma unroll
  for (int mask = 16; mask <= 32; mask <<= 1)
#pragma unroll
    for (int n = 0; n < 4; ++n)
      rmin[n] = fminf(rmin[n], __shfl_xor(rmin[n], mask));
  if (q == 0) {
#pragma unroll
    for (int n = 0; n < 4; ++n)
      atomicMin(&rowmin_u[wx * 64 + n * 16 + r16], __float_as_uint(rmin[n]));
  }
  // col-min: reduce across r16 (same w-col for equal q)
#pragma unroll
  for (int mask = 1; mask <= 8; mask <<= 1)
#pragma unroll
    for (int m = 0; m < 4; ++m)
#pragma unroll
      for (int j = 0; j < 4; ++j)
        cmin[m][j] = fminf(cmin[m][j], __shfl_xor(cmin[m][j], mask));
  if (r16 == 0) {
#pragma unroll
    for (int m = 0; m < 4; ++m)
#pragma unroll
      for (int j = 0; j < 4; ++j)
        atomicMin(&colmin_u[ww * 64 + m * 16 + q * 4 + j], __float_as_uint(cmin[m][j]));
  }
  __syncthreads();
  if (tid < 128) atomicMin(&rowmin_g[x0 + tid], rowmin_u[tid]);
  else           atomicMin(&colmin_g[w0 + (tid - 128)], colmin_u[tid - 128]);
}

// ---------------------------------------------------------------------------
// sqrt of final mins + fixed-order block sums.
// ---------------------------------------------------------------------------
__global__ __launch_bounds__(256) void minsqrt_sum(const unsigned int* __restrict__ mins,
                                                   float* __restrict__ out) {
  int idx = blockIdx.x * 256 + threadIdx.x;
  float s = sqrtf(__uint_as_float(mins[idx]));
#pragma unroll
  for (int mask = 1; mask < 64; mask <<= 1) s += __shfl_xor(s, mask);
  __shared__ float wsum[4];
  int wave = threadIdx.x >> 6, lane = threadIdx.x & 63;
  if (lane == 0) wsum[wave] = s;
  __syncthreads();
  if (threadIdx.x == 0) out[blockIdx.x] = wsum[0] + wsum[1] + wsum[2] + wsum[3];
}

__global__ void finalize_kernel(const float* __restrict__ rowp, const float* __restrict__ colp,
                                const float* __restrict__ recon, const float* __restrict__ kl,
                                const float* __restrict__ mmd, float* __restrict__ out) {
  int lane = threadIdx.x;  // 64 threads
  float rs = rowp[lane] + rowp[lane + 64];
  float cs = (lane < 16) ? colp[lane] : 0.0f;
#pragma unroll
  for (int mask = 1; mask < 64; mask <<= 1) {
    rs += __shfl_xor(rs, mask);
    cs += __shfl_xor(cs, mask);
  }
  if (lane == 0) {
    out[OUT_CVAE] = recon[0] + 0.5f * kl[0] + mmd[0];
    out[OUT_PROT] = 0.5f * (rs / (float)N_ROWS) + 0.5f * (cs / (float)P_DIM);
  }
}

extern "C" void kernel_launch(void* const* d_in, const int* in_sizes, int n_in,
                              void* d_out, int out_size, void* d_ws, size_t ws_size,
                              hipStream_t stream) {
  const float* x     = (const float*)d_in[0];
  const float* W     = (const float*)d_in[1];
  const float* recon = (const float*)d_in[2];
  const float* kl    = (const float*)d_in[3];
  const float* mmd   = (const float*)d_in[4];
  float* out    = (float*)d_out;
  float* xn     = out;
  float* logits = out + OUT_LOGITS;

  char* ws = (char*)d_ws;
  unsigned short* Xbf = (unsigned short*)ws;                 // 33,554,432 B
  unsigned short* Wbf = (unsigned short*)(ws + 33554432);    //  4,194,304 B
  float* w2          = (float*)(ws + 37748736);              //     16,384 B
  unsigned int* rmg  = (unsigned int*)(ws + 37765120);       //    131,072 B (32768)
  unsigned int* cmg  = (unsigned int*)(ws + 37896192);       //     16,384 B (4096)
  float* rowsums     = (float*)(ws + 37912576);              //        512 B (128)
  float* colsums     = (float*)(ws + 37913088);              //         64 B (16)

  init_mins<<<(32768 + 4096 + 255) / 256, 256, 0, stream>>>(rmg, 32768 + 4096);
  prep_kernel<1><<<N_ROWS / 4, 256, 0, stream>>>(x, xn, Xbf, nullptr);
  prep_kernel<0><<<P_DIM / 4, 256, 0, stream>>>(W, nullptr, Wbf, w2);
  gemm_fused<<<(N_ROWS / 128) * (P_DIM / 128), 256, 0, stream>>>(
      Wbf, Xbf, w2, logits, rmg, cmg);
  minsqrt_sum<<<N_ROWS / 256, 256, 0, stream>>>(rmg, rowsums);
  minsqrt_sum<<<P_DIM / 256, 256, 0, stream>>>(cmg, colsums);
  finalize_kernel<<<1, 64, 0, stream>>>(rowsums, colsums, recon, kl, mmd, out);
}